// Round 12
// baseline (363.936 us; speedup 1.0000x reference)
//
#include <hip/hip_runtime.h>
#include <stdint.h>

typedef unsigned short u16;
typedef unsigned int   u32;
typedef _Float16 f16_t;
typedef f16_t f16x8 __attribute__((ext_vector_type(8)));
typedef float  f32x4  __attribute__((ext_vector_type(4)));

#define BB 2
#define NN 2048
#define CC 2048
#define HH 16
#define DD 128
#define FF 6144
#define MM 4096

__device__ __forceinline__ u16 f2h(float f){
    f16_t h = (f16_t)f;
    return __builtin_bit_cast(u16, h);
}
__device__ __forceinline__ float h2f(u16 b){
    return (float)__builtin_bit_cast(f16_t, b);
}
__device__ __forceinline__ f32x4 MFMA(f16x8 a, f16x8 b, f32x4 c){
    return __builtin_amdgcn_mfma_f32_16x16x32_f16(a, b, c, 0, 0, 0);
}
__device__ __forceinline__ void gld16(const void* g, void* l){
    __builtin_amdgcn_global_load_lds(
        (const __attribute__((address_space(1))) void*)(g),
        (__attribute__((address_space(3))) void*)(l), 16, 0, 0);
}
#define SB0() __builtin_amdgcn_sched_barrier(0)

// ---------------- fp32 -> fp16 conversion ----------------
__global__ void k_f2h(const float* __restrict__ a, u16* __restrict__ o, int n4){
    int i = blockIdx.x * blockDim.x + threadIdx.x;
    int stride = gridDim.x * blockDim.x;
    for (; i < n4; i += stride){
        float4 v = ((const float4*)a)[i];
        ushort4 r; r.x = f2h(v.x); r.y = f2h(v.y); r.z = f2h(v.z); r.w = f2h(v.w);
        ((ushort4*)o)[i] = r;
    }
}

// ---------------- GEMM 256x256 (QKV): 512 thr, 8 waves, per-wave 128x64 ------
// Same R8-validated triple-buffer schedule (4 gld16/stage/thread, vmcnt 8/4/0),
// scaled to a 256^2 block tile: 12 ds_read_b128 per 32 MFMA (0.375 KB/MFMA vs
// 0.5 at 128^2) -> LDS-BW ceiling rises ~35% -> ~60% MfmaUtil.
// LDS XOR swizzle both sides (source col + read col) -> 0 conflicts.
__global__ __launch_bounds__(512, 2) void k_gemm256(
    const u16* __restrict__ A, const u16* __restrict__ Bw,
    u16* __restrict__ outb, int M, int N, int K)
{
    __shared__ u16 As[3][256 * 32];
    __shared__ u16 Bs[3][256 * 32];
    const int tid  = threadIdx.x;          // 0..511
    const int brow = blockIdx.y * 256;
    const int bcol = blockIdx.x * 256;
    const int w = tid >> 6, lane = tid & 63;
    const int wr = w >> 2;                 // 0..1: 128-row half
    const int wc = w & 3;                  // 0..3: 64-col quarter
    const int l15 = lane & 15, g = lane >> 4;
    const int sr  = tid >> 2;              // staged row 0..127 (+128)
    const int scz = ((tid & 3) ^ ((tid >> 3) & 3)) * 8;     // swizzled source col
    const int gx  = (g ^ ((l15 >> 1) & 3)) * 8;             // swizzled read col

    f32x4 acc[8][4];
    #pragma unroll
    for (int i = 0; i < 8; i++)
        #pragma unroll
        for (int j = 0; j < 4; j++){
            f32x4 z = {0.f, 0.f, 0.f, 0.f};
            acc[i][j] = z;
        }

    auto stage = [&](int buf, int k0){
        gld16(&A [(size_t)(brow + sr      ) * K + k0 + scz], &As[buf][w * 512]);
        gld16(&A [(size_t)(brow + sr + 128) * K + k0 + scz], &As[buf][4096 + w * 512]);
        gld16(&Bw[(size_t)(bcol + sr      ) * K + k0 + scz], &Bs[buf][w * 512]);
        gld16(&Bw[(size_t)(bcol + sr + 128) * K + k0 + scz], &Bs[buf][4096 + w * 512]);
    };

    stage(0, 0);
    stage(1, 32);
    int c = 0;
    for (int k0 = 0; k0 < K; k0 += 32){
        SB0();
        __builtin_amdgcn_s_barrier();          // A: readers of buf ct done
        SB0();
        int ct = c + 2; if (ct >= 3) ct -= 3;
        if (k0 + 64 < K){
            stage(ct, k0 + 64);
            asm volatile("s_waitcnt vmcnt(8)" ::: "memory");
        } else if (k0 + 32 < K){
            asm volatile("s_waitcnt vmcnt(4)" ::: "memory");
        } else {
            asm volatile("s_waitcnt vmcnt(0)" ::: "memory");
        }
        SB0();
        __builtin_amdgcn_s_barrier();          // B: everyone's K_t loads landed
        SB0();
        f16x8 fb[4];
        #pragma unroll
        for (int j = 0; j < 4; j++){
            int row = wc * 64 + j * 16 + l15;
            fb[j] = *(const f16x8*)&Bs[c][row * 32 + gx];
        }
        #pragma unroll
        for (int i = 0; i < 8; i++){
            int row = wr * 128 + i * 16 + l15;
            f16x8 fa = *(const f16x8*)&As[c][row * 32 + gx];
            #pragma unroll
            for (int j = 0; j < 4; j++) acc[i][j] = MFMA(fa, fb[j], acc[i][j]);
        }
        c = (c + 1 == 3) ? 0 : c + 1;
    }

    #pragma unroll
    for (int i = 0; i < 8; i++){
        #pragma unroll
        for (int j = 0; j < 4; j++){
            int colg = bcol + wc * 64 + j * 16 + l15;
            #pragma unroll
            for (int r = 0; r < 4; r++){
                int rowg = brow + wr * 128 + i * 16 + 4 * g + r;
                outb[(size_t)rowg * N + colg] = f2h(acc[i][j][r]);
            }
        }
    }
}

// ---------------- GEMM 128x128 (proj, R8-exact) ----------------
template<int OUTH>
__global__ __launch_bounds__(256) void k_gemm_bt(
    const u16* __restrict__ A, const u16* __restrict__ Bw,
    float* __restrict__ outf, u16* __restrict__ outb,
    const float* __restrict__ bias, int M, int N, int K)
{
    __shared__ u16 As[3][128 * 32];
    __shared__ u16 Bs[3][128 * 32];
    const int tid  = threadIdx.x;
    const int brow = blockIdx.y * 128;
    const int bcol = blockIdx.x * 128;
    const int w = tid >> 6, lane = tid & 63;
    const int wr = w >> 1, wc = w & 1;
    const int l15 = lane & 15, g = lane >> 4;
    const int sr  = tid >> 2;
    const int scz = ((tid & 3) ^ ((tid >> 3) & 3)) * 8;
    const int gx  = (g ^ ((l15 >> 1) & 3)) * 8;

    f32x4 acc[4][4];
    #pragma unroll
    for (int i = 0; i < 4; i++)
        #pragma unroll
        for (int j = 0; j < 4; j++){
            f32x4 z = {0.f, 0.f, 0.f, 0.f};
            acc[i][j] = z;
        }

    auto stage = [&](int buf, int k0){
        gld16(&Bw[(size_t)(bcol + sr) * K + k0 + scz],      &Bs[buf][w * 512]);
        gld16(&Bw[(size_t)(bcol + sr + 64) * K + k0 + scz], &Bs[buf][2048 + w * 512]);
        gld16(&A [(size_t)(brow + sr) * K + k0 + scz],      &As[buf][w * 512]);
        gld16(&A [(size_t)(brow + sr + 64) * K + k0 + scz], &As[buf][2048 + w * 512]);
    };

    stage(0, 0);
    stage(1, 32);
    int c = 0;
    for (int k0 = 0; k0 < K; k0 += 32){
        SB0();
        __builtin_amdgcn_s_barrier();          // A
        SB0();
        int ct = c + 2; if (ct >= 3) ct -= 3;
        if (k0 + 64 < K){
            stage(ct, k0 + 64);
            asm volatile("s_waitcnt vmcnt(8)" ::: "memory");
        } else if (k0 + 32 < K){
            asm volatile("s_waitcnt vmcnt(4)" ::: "memory");
        } else {
            asm volatile("s_waitcnt vmcnt(0)" ::: "memory");
        }
        SB0();
        __builtin_amdgcn_s_barrier();          // B
        SB0();
        f16x8 fb[4];
        #pragma unroll
        for (int j = 0; j < 4; j++){
            int row = wc * 64 + j * 16 + l15;
            fb[j] = *(const f16x8*)&Bs[c][row * 32 + gx];
        }
        #pragma unroll
        for (int i = 0; i < 4; i++){
            int row = wr * 64 + i * 16 + l15;
            f16x8 fa = *(const f16x8*)&As[c][row * 32 + gx];
            #pragma unroll
            for (int j = 0; j < 4; j++) acc[i][j] = MFMA(fa, fb[j], acc[i][j]);
        }
        c = (c + 1 == 3) ? 0 : c + 1;
    }

    #pragma unroll
    for (int i = 0; i < 4; i++){
        #pragma unroll
        for (int j = 0; j < 4; j++){
            int colg = bcol + wc * 64 + j * 16 + l15;
            #pragma unroll
            for (int r = 0; r < 4; r++){
                int rowg = brow + wr * 64 + i * 16 + 4 * g + r;
                float v = acc[i][j][r];
                if (OUTH) outb[(size_t)rowg * N + colg] = f2h(v);
                else      outf[(size_t)rowg * N + colg] = v + bias[colg];
            }
        }
    }
}

// ---------------- RMSNorm + RoPE (q,k only) -> (B,H,N,D), fp16 ----------------
__global__ __launch_bounds__(256) void k_norm_rope(
    const u16* __restrict__ qkv, const float* __restrict__ qw, const float* __restrict__ kw,
    const float* __restrict__ cosb, const float* __restrict__ sinb,
    u16* __restrict__ qout, u16* __restrict__ kout)
{
    const int m = blockIdx.x;           // 0..4095  (b*N + n)
    const int b = m >> 11;
    const int n = m & 2047;
    const int t = threadIdx.x;
    const size_t base = (size_t)m * FF;
    const int e0 = t * 8;
    const float SCL = 0.08838834764831845f * 1.4426950408889634f;

    float qv[8], kvv[8];
    uint4 qa = *(const uint4*)&qkv[base + e0];
    uint4 ka = *(const uint4*)&qkv[base + CC + e0];
    {
        u32 aa[4] = {qa.x, qa.y, qa.z, qa.w};
        u32 bb[4] = {ka.x, ka.y, ka.z, ka.w};
        #pragma unroll
        for (int i = 0; i < 4; i++){
            qv[2*i]   = h2f((u16)(aa[i] & 0xffff));
            qv[2*i+1] = h2f((u16)(aa[i] >> 16));
            kvv[2*i]   = h2f((u16)(bb[i] & 0xffff));
            kvv[2*i+1] = h2f((u16)(bb[i] >> 16));
        }
    }
    float sq = 0.f, sk = 0.f;
    #pragma unroll
    for (int i = 0; i < 8; i++){ sq += qv[i]*qv[i]; sk += kvv[i]*kvv[i]; }
    #pragma unroll
    for (int o = 32; o > 0; o >>= 1){ sq += __shfl_xor(sq, o); sk += __shfl_xor(sk, o); }
    __shared__ float red[8];
    if ((t & 63) == 0){ red[(t >> 6)*2] = sq; red[(t >> 6)*2 + 1] = sk; }
    __syncthreads();
    sq = red[0] + red[2] + red[4] + red[6];
    sk = red[1] + red[3] + red[5] + red[7];
    const float rq = rsqrtf(sq * (1.f / 2048.f) + 1e-5f);
    const float rk = rsqrtf(sk * (1.f / 2048.f) + 1e-5f);

    const int h  = t >> 4;
    const int d0 = (t & 15) * 8;
    const float* cp = cosb + (size_t)n * DD + d0;
    const float* sp = sinb + (size_t)n * DD + d0;
    float qo[8], ko[8];
    #pragma unroll
    for (int j = 0; j < 8; j += 2){
        float c0 = cp[j], c1 = cp[j+1], s0 = sp[j], s1 = sp[j+1];
        float x0 = qv[j]   * rq * qw[e0 + j];
        float x1 = qv[j+1] * rq * qw[e0 + j + 1];
        qo[j]   = (x0 * c0 - x1 * s0) * SCL;
        qo[j+1] = (x1 * c1 + x0 * s1) * SCL;
        float y0 = kvv[j]   * rk * kw[e0 + j];
        float y1 = kvv[j+1] * rk * kw[e0 + j + 1];
        ko[j]   = y0 * c0 - y1 * s0;
        ko[j+1] = y1 * c1 + y0 * s1;
    }
    const size_t obase = ((size_t)(b * HH + h) * NN + n) * DD + d0;
    uint4 pq, pk;
    pq.x = (u32)f2h(qo[0]) | ((u32)f2h(qo[1]) << 16);
    pq.y = (u32)f2h(qo[2]) | ((u32)f2h(qo[3]) << 16);
    pq.z = (u32)f2h(qo[4]) | ((u32)f2h(qo[5]) << 16);
    pq.w = (u32)f2h(qo[6]) | ((u32)f2h(qo[7]) << 16);
    pk.x = (u32)f2h(ko[0]) | ((u32)f2h(ko[1]) << 16);
    pk.y = (u32)f2h(ko[2]) | ((u32)f2h(ko[3]) << 16);
    pk.z = (u32)f2h(ko[4]) | ((u32)f2h(ko[5]) << 16);
    pk.w = (u32)f2h(ko[6]) | ((u32)f2h(ko[7]) << 16);
    *(uint4*)&qout[obase] = pq;
    *(uint4*)&kout[obase] = pk;
}

// ---------------- V transpose: qkv v-slice (B,N,H,D) -> (BH, D, N) ----------------
__global__ __launch_bounds__(256) void k_vtrans(const u16* __restrict__ qkv, u16* __restrict__ Vt){
    __shared__ u16 t[64 * 66];
    const int bh = blockIdx.z;
    const int b = bh >> 4, h = bh & 15;
    const int n0 = blockIdx.x * 64, d0 = blockIdx.y * 64;
    const int tid = threadIdx.x;
    const int q = tid & 7, p = tid >> 3;
    #pragma unroll
    for (int it = 0; it < 2; it++){
        int r = p + it * 32;
        const u16* src = qkv + (size_t)(b * NN + n0 + r) * FF + 2 * CC + h * DD + d0 + q * 8;
        uint4 v = *(const uint4*)src;
        u32* dst = (u32*)&t[r * 66 + q * 8];
        dst[0] = v.x; dst[1] = v.y; dst[2] = v.z; dst[3] = v.w;
    }
    __syncthreads();
    #pragma unroll
    for (int it = 0; it < 2; it++){
        int rd = p + it * 32;
        u16 o[8];
        #pragma unroll
        for (int j = 0; j < 8; j++) o[j] = t[(q * 8 + j) * 66 + rd];
        *(uint4*)(Vt + ((size_t)bh * DD + d0 + rd) * NN + n0 + q * 8) = *(uint4*)o;
    }
}

// ---------------- attention v6: LDS-staged K/V, 2-phase dbuf ----------
__global__ __launch_bounds__(256, 2) void k_attn6(
    const u16* __restrict__ Q, const u16* __restrict__ Kt, const u16* __restrict__ Vt2,
    u16* __restrict__ O)
{
    __shared__ u16 Kbuf[2][8192];   // 16 slots: s = hh*8 + t*4 + c
    __shared__ u16 Vbuf[2][8192];   // 16 slots: s = hh*8 + tb
    const int tid = threadIdx.x;
    const int w = tid >> 6, lane = tid & 63;
    const int l15 = lane & 15, g = lane >> 4;
    const int flat = blockIdx.x;
    const int lid  = (flat & 7) * 64 + (flat >> 3);   // bijective XCD swizzle (512 blocks)
    const int qb = lid & 15;
    const int h  = (lid >> 4) & 15;
    const int b  = lid >> 8;
    const size_t hb  = (size_t)(b * HH + h) * NN * DD;  // Q, K: (N,D)
    const size_t hbT = (size_t)(b * HH + h) * DD * NN;  // Vt2: (D,N)
    const int qbase = qb * 128 + w * 32;
    const int mperm = 8 * (l15 >> 2) + (l15 & 3);

    f16x8 qf[2][4];
    #pragma unroll
    for (int u = 0; u < 2; u++){
        const u16* qrow = Q + hb + (size_t)(qbase + u * 16 + l15) * DD;
        #pragma unroll
        for (int c = 0; c < 4; c++)
            qf[u][c] = *(const f16x8*)(qrow + c * 32 + 8 * g);
    }

    f32x4 oacc[2][8];
    #pragma unroll
    for (int u = 0; u < 2; u++)
        #pragma unroll
        for (int tb = 0; tb < 8; tb++){ f32x4 z = {0.f,0.f,0.f,0.f}; oacc[u][tb] = z; }
    float lsum0 = 0.f, lsum1 = 0.f;

    auto stage = [&](int buf, int kv0){
        #pragma unroll
        for (int it = 0; it < 8; it++){
            int s = it * 4 + w;                 // 0..31, each slot once
            if (s < 16){
                int hh = s >> 3, t = (s >> 2) & 1, c = s & 3;
                gld16(&Kt[hb + (size_t)(kv0 + 32 * hh + 4 * t + mperm) * DD + 32 * c + 8 * g],
                      &Kbuf[buf][s * 512]);
            } else {
                int s2 = s - 16;
                int hh = s2 >> 3, tb = s2 & 7;
                gld16(&Vt2[hbT + (size_t)(tb * 16 + l15) * NN + kv0 + 32 * hh + 8 * g],
                      &Vbuf[buf][s2 * 512]);
            }
        }
    };

    int cur = 0;
    stage(0, 0);
    for (int kv0 = 0; kv0 < NN; kv0 += 64){
        __syncthreads();                         // buf[cur] staged; prev reads done
        if (kv0 + 64 < NN) stage(cur ^ 1, kv0 + 64);
        const u16* kb = &Kbuf[cur][0] + lane * 8;
        const u16* vb = &Vbuf[cur][0] + lane * 8;

        f32x4 st[2][4];
        #pragma unroll
        for (int hh = 0; hh < 2; hh++)
            #pragma unroll
            for (int q = 0; q < 4; q++){ f32x4 z = {0.f,0.f,0.f,0.f}; st[hh][q] = z; }
        __builtin_amdgcn_s_setprio(1);
        #pragma unroll
        for (int hh = 0; hh < 2; hh++){
            #pragma unroll
            for (int c = 0; c < 4; c++){
                f16x8 kf0 = *(const f16x8*)(kb + (hh * 8 + c) * 512);
                f16x8 kf1 = *(const f16x8*)(kb + (hh * 8 + 4 + c) * 512);
                st[hh][0] = MFMA(kf0, qf[0][c], st[hh][0]);
                st[hh][1] = MFMA(kf0, qf[1][c], st[hh][1]);
                st[hh][2] = MFMA(kf1, qf[0][c], st[hh][2]);
                st[hh][3] = MFMA(kf1, qf[1][c], st[hh][3]);
            }
        }
        __builtin_amdgcn_s_setprio(0);

        f16x8 pf[2][2];
        #pragma unroll
        for (int hh = 0; hh < 2; hh++){
            #pragma unroll
            for (int r = 0; r < 4; r++){
                float e00 = exp2f(st[hh][0][r]), e10 = exp2f(st[hh][2][r]);
                float e01 = exp2f(st[hh][1][r]), e11 = exp2f(st[hh][3][r]);
                lsum0 += e00 + e10;
                lsum1 += e01 + e11;
                pf[hh][0][r] = (f16_t)e00; pf[hh][0][r + 4] = (f16_t)e10;
                pf[hh][1][r] = (f16_t)e01; pf[hh][1][r + 4] = (f16_t)e11;
            }
        }

        __builtin_amdgcn_s_setprio(1);
        #pragma unroll
        for (int hh = 0; hh < 2; hh++){
            #pragma unroll
            for (int tb = 0; tb < 8; tb++){
                f16x8 vf = *(const f16x8*)(vb + (hh * 8 + tb) * 512);
                oacc[0][tb] = MFMA(pf[hh][0], vf, oacc[0][tb]);
                oacc[1][tb] = MFMA(pf[hh][1], vf, oacc[1][tb]);
            }
        }
        __builtin_amdgcn_s_setprio(0);
        cur ^= 1;
    }

    lsum0 += __shfl_xor(lsum0, 16); lsum0 += __shfl_xor(lsum0, 32);
    lsum1 += __shfl_xor(lsum1, 16); lsum1 += __shfl_xor(lsum1, 32);
    float linv0 = 1.f / lsum0, linv1 = 1.f / lsum1;
    float li0[4], li1[4];
    #pragma unroll
    for (int r = 0; r < 4; r++){
        li0[r] = __shfl(linv0, 4 * g + r);
        li1[r] = __shfl(linv1, 4 * g + r);
    }

    #pragma unroll
    for (int tb = 0; tb < 8; tb++){
        #pragma unroll
        for (int r = 0; r < 4; r++){
            int q0 = qbase + 4 * g + r;
            O[(size_t)(b * NN + q0) * CC + h * DD + tb * 16 + l15] = f2h(oacc[0][tb][r] * li0[r]);
            int q1 = qbase + 16 + 4 * g + r;
            O[(size_t)(b * NN + q1) * CC + h * DD + tb * 16 + l15] = f2h(oacc[1][tb][r] * li1[r]);
        }
    }
}

// ---------------- launch ----------------
extern "C" void kernel_launch(void* const* d_in, const int* in_sizes, int n_in,
                              void* d_out, int out_size, void* d_ws, size_t ws_size,
                              hipStream_t stream) {
    const float* x      = (const float*)d_in[0];
    const float* w_qkv  = (const float*)d_in[1];
    const float* qw     = (const float*)d_in[2];
    const float* kw     = (const float*)d_in[3];
    const float* cosb   = (const float*)d_in[4];
    const float* sinb   = (const float*)d_in[5];
    const float* w_proj = (const float*)d_in[6];
    const float* b_proj = (const float*)d_in[7];
    float* out = (float*)d_out;

    const size_t sz_xh   = (size_t)MM * CC * 2;        // 16 MiB
    const size_t sz_wqkv = (size_t)FF * CC * 2;        // 24 MiB
    const size_t sz_wprj = (size_t)CC * CC * 2;        // 8 MiB
    const size_t sz_qkv  = (size_t)MM * FF * 2;        // 48 MiB
    const size_t sz_t    = (size_t)BB * HH * NN * DD * 2; // 16 MiB each
    const size_t need = sz_xh + sz_wqkv + sz_wprj + sz_qkv + sz_t*3 + sz_xh;
    if (ws_size < need) return;

    char* ws = (char*)d_ws;
    size_t off = 0;
    auto alloc = [&](size_t bytes){ void* p = ws + off; off += (bytes + 255) & ~(size_t)255; return p; };
    u16* x_h     = (u16*)alloc(sz_xh);
    u16* wqkv_h  = (u16*)alloc(sz_wqkv);
    u16* wprj_h  = (u16*)alloc(sz_wprj);
    u16* qkv     = (u16*)alloc(sz_qkv);
    u16* qr      = (u16*)alloc(sz_t);
    u16* kr      = (u16*)alloc(sz_t);
    u16* vt2     = (u16*)alloc(sz_t);   // transposed V (B,H,D,N), read from qkv directly
    u16* ob      = (u16*)alloc(sz_xh);

    k_f2h<<<2048, 256, 0, stream>>>(x, x_h, MM * CC / 4);
    k_f2h<<<2048, 256, 0, stream>>>(w_qkv, wqkv_h, FF * CC / 4);
    k_f2h<<<1024, 256, 0, stream>>>(w_proj, wprj_h, CC * CC / 4);
    k_gemm256<<<dim3(FF / 256, MM / 256), 512, 0, stream>>>(
        x_h, wqkv_h, qkv, MM, FF, CC);
    k_norm_rope<<<MM, 256, 0, stream>>>(qkv, qw, kw, cosb, sinb, qr, kr);
    k_vtrans<<<dim3(NN / 64, DD / 64, BB * HH), 256, 0, stream>>>(qkv, vt2);
    k_attn6<<<512, 256, 0, stream>>>(qr, kr, vt2, ob);
    k_gemm_bt<0><<<dim3(CC / 128, MM / 128), 256, 0, stream>>>(
        ob, wprj_h, out, nullptr, b_proj, MM, CC, CC);
}

// Round 13
// 339.671 us; speedup vs baseline: 1.0714x; 1.0714x over previous
//
#include <hip/hip_runtime.h>
#include <stdint.h>

typedef unsigned short u16;
typedef unsigned int   u32;
typedef _Float16 f16_t;
typedef f16_t f16x8 __attribute__((ext_vector_type(8)));
typedef float  f32x4  __attribute__((ext_vector_type(4)));

#define BB 2
#define NN 2048
#define CC 2048
#define HH 16
#define DD 128
#define FF 6144
#define MM 4096

__device__ __forceinline__ u16 f2h(float f){
    f16_t h = (f16_t)f;
    return __builtin_bit_cast(u16, h);
}
__device__ __forceinline__ float h2f(u16 b){
    return (float)__builtin_bit_cast(f16_t, b);
}
__device__ __forceinline__ f32x4 MFMA(f16x8 a, f16x8 b, f32x4 c){
    return __builtin_amdgcn_mfma_f32_16x16x32_f16(a, b, c, 0, 0, 0);
}
__device__ __forceinline__ void gld16(const void* g, void* l){
    __builtin_amdgcn_global_load_lds(
        (const __attribute__((address_space(1))) void*)(g),
        (__attribute__((address_space(3))) void*)(l), 16, 0, 0);
}
#define SB0() __builtin_amdgcn_sched_barrier(0)

// ---------------- fp32 -> fp16 conversion (x, w_qkv, w_proj in one launch) ----
__global__ void k_f2h3(const float* __restrict__ a0, u16* __restrict__ o0, int n0,
                       const float* __restrict__ a1, u16* __restrict__ o1, int n1,
                       const float* __restrict__ a2, u16* __restrict__ o2, int n2){
    int i = blockIdx.x * blockDim.x + threadIdx.x;
    int stride = gridDim.x * blockDim.x;
    int nt = n0 + n1 + n2;
    for (; i < nt; i += stride){
        const float4* src; ushort4* dst; int j;
        if (i < n0){ src = (const float4*)a0; dst = (ushort4*)o0; j = i; }
        else if (i < n0 + n1){ src = (const float4*)a1; dst = (ushort4*)o1; j = i - n0; }
        else { src = (const float4*)a2; dst = (ushort4*)o2; j = i - n0 - n1; }
        float4 v = src[j];
        ushort4 r; r.x = f2h(v.x); r.y = f2h(v.y); r.z = f2h(v.z); r.w = f2h(v.w);
        dst[j] = r;
    }
}

// ---------------- GEMM 128x128 (R8-exact, best measured: 785 TF) ----------------
// Counted-vmcnt triple buffer: raw barriers + s_waitcnt vmcnt(8).
//   barrier A : all waves done READING buf ct (read last iter)
//   stage K_{t+2} -> ct ; vmcnt(8) = own K_t loads landed  [tail 4 / 0]
//   barrier B : everyone's K_t loads landed ; ds_read + 16 MFMA
// LDS XOR swizzle both sides (global source col + ds_read col) -> 0 conflicts.
template<int OUTH>
__global__ __launch_bounds__(256) void k_gemm_bt(
    const u16* __restrict__ A, const u16* __restrict__ Bw,
    float* __restrict__ outf, u16* __restrict__ outb,
    const float* __restrict__ bias, int M, int N, int K)
{
    __shared__ u16 As[3][128 * 32];
    __shared__ u16 Bs[3][128 * 32];
    const int tid  = threadIdx.x;
    const int brow = blockIdx.y * 128;
    const int bcol = blockIdx.x * 128;
    const int w = tid >> 6, lane = tid & 63;
    const int wr = w >> 1, wc = w & 1;
    const int l15 = lane & 15, g = lane >> 4;
    const int sr  = tid >> 2;
    const int scz = ((tid & 3) ^ ((tid >> 3) & 3)) * 8;
    const int gx  = (g ^ ((l15 >> 1) & 3)) * 8;

    f32x4 acc[4][4];
    #pragma unroll
    for (int i = 0; i < 4; i++)
        #pragma unroll
        for (int j = 0; j < 4; j++){
            f32x4 z = {0.f, 0.f, 0.f, 0.f};
            acc[i][j] = z;
        }

    auto stage = [&](int buf, int k0){
        gld16(&Bw[(size_t)(bcol + sr) * K + k0 + scz],      &Bs[buf][w * 512]);
        gld16(&Bw[(size_t)(bcol + sr + 64) * K + k0 + scz], &Bs[buf][2048 + w * 512]);
        gld16(&A [(size_t)(brow + sr) * K + k0 + scz],      &As[buf][w * 512]);
        gld16(&A [(size_t)(brow + sr + 64) * K + k0 + scz], &As[buf][2048 + w * 512]);
    };

    stage(0, 0);
    stage(1, 32);
    int c = 0;
    for (int k0 = 0; k0 < K; k0 += 32){
        SB0();
        __builtin_amdgcn_s_barrier();          // A
        SB0();
        int ct = c + 2; if (ct >= 3) ct -= 3;
        if (k0 + 64 < K){
            stage(ct, k0 + 64);
            asm volatile("s_waitcnt vmcnt(8)" ::: "memory");
        } else if (k0 + 32 < K){
            asm volatile("s_waitcnt vmcnt(4)" ::: "memory");
        } else {
            asm volatile("s_waitcnt vmcnt(0)" ::: "memory");
        }
        SB0();
        __builtin_amdgcn_s_barrier();          // B
        SB0();
        f16x8 fb[4];
        #pragma unroll
        for (int j = 0; j < 4; j++){
            int row = wc * 64 + j * 16 + l15;
            fb[j] = *(const f16x8*)&Bs[c][row * 32 + gx];
        }
        #pragma unroll
        for (int i = 0; i < 4; i++){
            int row = wr * 64 + i * 16 + l15;
            f16x8 fa = *(const f16x8*)&As[c][row * 32 + gx];
            #pragma unroll
            for (int j = 0; j < 4; j++) acc[i][j] = MFMA(fa, fb[j], acc[i][j]);
        }
        c = (c + 1 == 3) ? 0 : c + 1;
    }

    #pragma unroll
    for (int i = 0; i < 4; i++){
        #pragma unroll
        for (int j = 0; j < 4; j++){
            int colg = bcol + wc * 64 + j * 16 + l15;
            #pragma unroll
            for (int r = 0; r < 4; r++){
                int rowg = brow + wr * 64 + i * 16 + 4 * g + r;
                float v = acc[i][j][r];
                if (OUTH) outb[(size_t)rowg * N + colg] = f2h(v);
                else      outf[(size_t)rowg * N + colg] = v + bias[colg];
            }
        }
    }
}

// ---------------- RMSNorm + RoPE (q,k only) -> (B,H,N,D), fp16 ----------------
__global__ __launch_bounds__(256) void k_norm_rope(
    const u16* __restrict__ qkv, const float* __restrict__ qw, const float* __restrict__ kw,
    const float* __restrict__ cosb, const float* __restrict__ sinb,
    u16* __restrict__ qout, u16* __restrict__ kout)
{
    const int m = blockIdx.x;           // 0..4095  (b*N + n)
    const int b = m >> 11;
    const int n = m & 2047;
    const int t = threadIdx.x;
    const size_t base = (size_t)m * FF;
    const int e0 = t * 8;
    const float SCL = 0.08838834764831845f * 1.4426950408889634f;

    float qv[8], kvv[8];
    uint4 qa = *(const uint4*)&qkv[base + e0];
    uint4 ka = *(const uint4*)&qkv[base + CC + e0];
    {
        u32 aa[4] = {qa.x, qa.y, qa.z, qa.w};
        u32 bb[4] = {ka.x, ka.y, ka.z, ka.w};
        #pragma unroll
        for (int i = 0; i < 4; i++){
            qv[2*i]   = h2f((u16)(aa[i] & 0xffff));
            qv[2*i+1] = h2f((u16)(aa[i] >> 16));
            kvv[2*i]   = h2f((u16)(bb[i] & 0xffff));
            kvv[2*i+1] = h2f((u16)(bb[i] >> 16));
        }
    }
    float sq = 0.f, sk = 0.f;
    #pragma unroll
    for (int i = 0; i < 8; i++){ sq += qv[i]*qv[i]; sk += kvv[i]*kvv[i]; }
    #pragma unroll
    for (int o = 32; o > 0; o >>= 1){ sq += __shfl_xor(sq, o); sk += __shfl_xor(sk, o); }
    __shared__ float red[8];
    if ((t & 63) == 0){ red[(t >> 6)*2] = sq; red[(t >> 6)*2 + 1] = sk; }
    __syncthreads();
    sq = red[0] + red[2] + red[4] + red[6];
    sk = red[1] + red[3] + red[5] + red[7];
    const float rq = rsqrtf(sq * (1.f / 2048.f) + 1e-5f);
    const float rk = rsqrtf(sk * (1.f / 2048.f) + 1e-5f);

    const int h  = t >> 4;
    const int d0 = (t & 15) * 8;
    const float* cp = cosb + (size_t)n * DD + d0;
    const float* sp = sinb + (size_t)n * DD + d0;
    float qo[8], ko[8];
    #pragma unroll
    for (int j = 0; j < 8; j += 2){
        float c0 = cp[j], c1 = cp[j+1], s0 = sp[j], s1 = sp[j+1];
        float x0 = qv[j]   * rq * qw[e0 + j];
        float x1 = qv[j+1] * rq * qw[e0 + j + 1];
        qo[j]   = (x0 * c0 - x1 * s0) * SCL;
        qo[j+1] = (x1 * c1 + x0 * s1) * SCL;
        float y0 = kvv[j]   * rk * kw[e0 + j];
        float y1 = kvv[j+1] * rk * kw[e0 + j + 1];
        ko[j]   = y0 * c0 - y1 * s0;
        ko[j+1] = y1 * c1 + y0 * s1;
    }
    const size_t obase = ((size_t)(b * HH + h) * NN + n) * DD + d0;
    uint4 pq, pk;
    pq.x = (u32)f2h(qo[0]) | ((u32)f2h(qo[1]) << 16);
    pq.y = (u32)f2h(qo[2]) | ((u32)f2h(qo[3]) << 16);
    pq.z = (u32)f2h(qo[4]) | ((u32)f2h(qo[5]) << 16);
    pq.w = (u32)f2h(qo[6]) | ((u32)f2h(qo[7]) << 16);
    pk.x = (u32)f2h(ko[0]) | ((u32)f2h(ko[1]) << 16);
    pk.y = (u32)f2h(ko[2]) | ((u32)f2h(ko[3]) << 16);
    pk.z = (u32)f2h(ko[4]) | ((u32)f2h(ko[5]) << 16);
    pk.w = (u32)f2h(ko[6]) | ((u32)f2h(ko[7]) << 16);
    *(uint4*)&qout[obase] = pq;
    *(uint4*)&kout[obase] = pk;
}

// ---------------- V transpose: qkv v-slice (B,N,H,D) -> (BH, D, N) ----------------
__global__ __launch_bounds__(256) void k_vtrans(const u16* __restrict__ qkv, u16* __restrict__ Vt){
    __shared__ u16 t[64 * 66];
    const int bh = blockIdx.z;
    const int b = bh >> 4, h = bh & 15;
    const int n0 = blockIdx.x * 64, d0 = blockIdx.y * 64;
    const int tid = threadIdx.x;
    const int q = tid & 7, p = tid >> 3;
    #pragma unroll
    for (int it = 0; it < 2; it++){
        int r = p + it * 32;
        const u16* src = qkv + (size_t)(b * NN + n0 + r) * FF + 2 * CC + h * DD + d0 + q * 8;
        uint4 v = *(const uint4*)src;
        u32* dst = (u32*)&t[r * 66 + q * 8];
        dst[0] = v.x; dst[1] = v.y; dst[2] = v.z; dst[3] = v.w;
    }
    __syncthreads();
    #pragma unroll
    for (int it = 0; it < 2; it++){
        int rd = p + it * 32;
        u16 o[8];
        #pragma unroll
        for (int j = 0; j < 8; j++) o[j] = t[(q * 8 + j) * 66 + rd];
        *(uint4*)(Vt + ((size_t)bh * DD + d0 + rd) * NN + n0 + q * 8) = *(uint4*)o;
    }
}

// ---------------- attention v7: 64 q-rows/wave (2x arithmetic intensity) ----------
// Same validated LDS staging + 2-phase dbuf as attn5/6; each K/V fragment now
// feeds 4 MFMAs (4 q-sub-tiles) instead of 2. Grid 256 = 1 block/CU, 1 wave/SIMD
// -> 512-reg budget (oacc 128 + qf 64 + st 32, no spill).
__global__ __launch_bounds__(256, 1) void k_attn7(
    const u16* __restrict__ Q, const u16* __restrict__ Kt, const u16* __restrict__ Vt2,
    u16* __restrict__ O)
{
    __shared__ u16 Kbuf[2][8192];   // 16 slots: s = hh*8 + t*4 + c
    __shared__ u16 Vbuf[2][8192];   // 16 slots: s = hh*8 + tb
    const int tid = threadIdx.x;
    const int w = tid >> 6, lane = tid & 63;
    const int l15 = lane & 15, g = lane >> 4;
    const int flat = blockIdx.x;
    const int lid  = (flat & 7) * 32 + (flat >> 3);   // bijective XCD swizzle (256 blocks)
    const int qb = lid & 7;
    const int h  = (lid >> 3) & 15;
    const int b  = lid >> 7;
    const size_t hb  = (size_t)(b * HH + h) * NN * DD;  // Q, K: (N,D)
    const size_t hbT = (size_t)(b * HH + h) * DD * NN;  // Vt2: (D,N)
    const int qbase = qb * 256 + w * 64;
    const int mperm = 8 * (l15 >> 2) + (l15 & 3);

    f16x8 qf[4][4];
    #pragma unroll
    for (int u = 0; u < 4; u++){
        const u16* qrow = Q + hb + (size_t)(qbase + u * 16 + l15) * DD;
        #pragma unroll
        for (int c = 0; c < 4; c++)
            qf[u][c] = *(const f16x8*)(qrow + c * 32 + 8 * g);
    }

    f32x4 oacc[4][8];
    #pragma unroll
    for (int u = 0; u < 4; u++)
        #pragma unroll
        for (int tb = 0; tb < 8; tb++){ f32x4 z = {0.f,0.f,0.f,0.f}; oacc[u][tb] = z; }
    float lsum[4] = {0.f, 0.f, 0.f, 0.f};

    auto stage = [&](int buf, int kv0){
        #pragma unroll
        for (int it = 0; it < 8; it++){
            int s = it * 4 + w;                 // 0..31, each slot once
            if (s < 16){
                int hh = s >> 3, t = (s >> 2) & 1, c = s & 3;
                gld16(&Kt[hb + (size_t)(kv0 + 32 * hh + 4 * t + mperm) * DD + 32 * c + 8 * g],
                      &Kbuf[buf][s * 512]);
            } else {
                int s2 = s - 16;
                int hh = s2 >> 3, tb = s2 & 7;
                gld16(&Vt2[hbT + (size_t)(tb * 16 + l15) * NN + kv0 + 32 * hh + 8 * g],
                      &Vbuf[buf][s2 * 512]);
            }
        }
    };

    int cur = 0;
    stage(0, 0);
    for (int kv0 = 0; kv0 < NN; kv0 += 64){
        __syncthreads();                         // buf[cur] staged; prev reads done
        if (kv0 + 64 < NN) stage(cur ^ 1, kv0 + 64);
        const u16* kb = &Kbuf[cur][0] + lane * 8;
        const u16* vb = &Vbuf[cur][0] + lane * 8;
        #pragma unroll
        for (int hh = 0; hh < 2; hh++){
            f32x4 st[4][2];
            #pragma unroll
            for (int u = 0; u < 4; u++){
                f32x4 z = {0.f,0.f,0.f,0.f};
                st[u][0] = z; st[u][1] = z;
            }
            __builtin_amdgcn_s_setprio(1);
            #pragma unroll
            for (int c = 0; c < 4; c++){
                f16x8 kf0 = *(const f16x8*)(kb + (hh * 8 + c) * 512);
                f16x8 kf1 = *(const f16x8*)(kb + (hh * 8 + 4 + c) * 512);
                #pragma unroll
                for (int u = 0; u < 4; u++){
                    st[u][0] = MFMA(kf0, qf[u][c], st[u][0]);
                    st[u][1] = MFMA(kf1, qf[u][c], st[u][1]);
                }
            }
            __builtin_amdgcn_s_setprio(0);
            f16x8 pf[4];
            #pragma unroll
            for (int u = 0; u < 4; u++){
                #pragma unroll
                for (int r = 0; r < 4; r++){
                    float e0 = exp2f(st[u][0][r]);
                    float e1 = exp2f(st[u][1][r]);
                    lsum[u] += e0 + e1;
                    pf[u][r] = (f16_t)e0; pf[u][r + 4] = (f16_t)e1;
                }
            }
            __builtin_amdgcn_s_setprio(1);
            #pragma unroll
            for (int tb = 0; tb < 8; tb++){
                f16x8 vf = *(const f16x8*)(vb + (hh * 8 + tb) * 512);
                #pragma unroll
                for (int u = 0; u < 4; u++)
                    oacc[u][tb] = MFMA(pf[u], vf, oacc[u][tb]);
            }
            __builtin_amdgcn_s_setprio(0);
        }
        cur ^= 1;
    }

    float li[4][4];
    #pragma unroll
    for (int u = 0; u < 4; u++){
        lsum[u] += __shfl_xor(lsum[u], 16);
        lsum[u] += __shfl_xor(lsum[u], 32);
        float linv = 1.f / lsum[u];
        #pragma unroll
        for (int r = 0; r < 4; r++) li[u][r] = __shfl(linv, 4 * g + r);
    }

    #pragma unroll
    for (int u = 0; u < 4; u++){
        #pragma unroll
        for (int tb = 0; tb < 8; tb++){
            #pragma unroll
            for (int r = 0; r < 4; r++){
                int q0 = qbase + u * 16 + 4 * g + r;
                O[(size_t)(b * NN + q0) * CC + h * DD + tb * 16 + l15] = f2h(oacc[u][tb][r] * li[u][r]);
            }
        }
    }
}

// ---------------- launch ----------------
extern "C" void kernel_launch(void* const* d_in, const int* in_sizes, int n_in,
                              void* d_out, int out_size, void* d_ws, size_t ws_size,
                              hipStream_t stream) {
    const float* x      = (const float*)d_in[0];
    const float* w_qkv  = (const float*)d_in[1];
    const float* qw     = (const float*)d_in[2];
    const float* kw     = (const float*)d_in[3];
    const float* cosb   = (const float*)d_in[4];
    const float* sinb   = (const float*)d_in[5];
    const float* w_proj = (const float*)d_in[6];
    const float* b_proj = (const float*)d_in[7];
    float* out = (float*)d_out;

    const size_t sz_xh   = (size_t)MM * CC * 2;        // 16 MiB
    const size_t sz_wqkv = (size_t)FF * CC * 2;        // 24 MiB
    const size_t sz_wprj = (size_t)CC * CC * 2;        // 8 MiB
    const size_t sz_qkv  = (size_t)MM * FF * 2;        // 48 MiB
    const size_t sz_t    = (size_t)BB * HH * NN * DD * 2; // 16 MiB each
    const size_t need = sz_xh + sz_wqkv + sz_wprj + sz_qkv + sz_t*3 + sz_xh;
    if (ws_size < need) return;

    char* ws = (char*)d_ws;
    size_t off = 0;
    auto alloc = [&](size_t bytes){ void* p = ws + off; off += (bytes + 255) & ~(size_t)255; return p; };
    u16* x_h     = (u16*)alloc(sz_xh);
    u16* wqkv_h  = (u16*)alloc(sz_wqkv);
    u16* wprj_h  = (u16*)alloc(sz_wprj);
    u16* qkv     = (u16*)alloc(sz_qkv);
    u16* qr      = (u16*)alloc(sz_t);
    u16* kr      = (u16*)alloc(sz_t);
    u16* vt2     = (u16*)alloc(sz_t);   // transposed V (B,H,D,N), read from qkv directly
    u16* ob      = (u16*)alloc(sz_xh);

    k_f2h3<<<2048, 256, 0, stream>>>(x, x_h, MM * CC / 4,
                                     w_qkv, wqkv_h, FF * CC / 4,
                                     w_proj, wprj_h, CC * CC / 4);
    k_gemm_bt<1><<<dim3(FF / 128, MM / 128), 256, 0, stream>>>(
        x_h, wqkv_h, nullptr, qkv, nullptr, MM, FF, CC);
    k_norm_rope<<<MM, 256, 0, stream>>>(qkv, qw, kw, cosb, sinb, qr, kr);
    k_vtrans<<<dim3(NN / 64, DD / 64, BB * HH), 256, 0, stream>>>(qkv, vt2);
    k_attn7<<<256, 256, 0, stream>>>(qr, kr, vt2, ob);
    k_gemm_bt<0><<<dim3(CC / 128, MM / 128), 256, 0, stream>>>(
        ob, wprj_h, out, nullptr, b_proj, MM, CC, CC);
}

// Round 14
// 313.934 us; speedup vs baseline: 1.1593x; 1.0820x over previous
//
#include <hip/hip_runtime.h>
#include <stdint.h>

typedef unsigned short u16;
typedef unsigned int   u32;
typedef _Float16 f16_t;
typedef f16_t f16x8 __attribute__((ext_vector_type(8)));
typedef float  f32x4  __attribute__((ext_vector_type(4)));

#define BB 2
#define NN 2048
#define CC 2048
#define HH 16
#define DD 128
#define FF 6144
#define MM 4096

__device__ __forceinline__ u16 f2h(float f){
    f16_t h = (f16_t)f;
    return __builtin_bit_cast(u16, h);
}
__device__ __forceinline__ float h2f(u16 b){
    return (float)__builtin_bit_cast(f16_t, b);
}
__device__ __forceinline__ f32x4 MFMA(f16x8 a, f16x8 b, f32x4 c){
    return __builtin_amdgcn_mfma_f32_16x16x32_f16(a, b, c, 0, 0, 0);
}
__device__ __forceinline__ void gld16(const void* g, void* l){
    __builtin_amdgcn_global_load_lds(
        (const __attribute__((address_space(1))) void*)(g),
        (__attribute__((address_space(3))) void*)(l), 16, 0, 0);
}
#define SB0() __builtin_amdgcn_sched_barrier(0)

// ---------------- fp32 -> fp16 conversion (x, w_qkv, w_proj in one launch) ----
__global__ void k_f2h3(const float* __restrict__ a0, u16* __restrict__ o0, int n0,
                       const float* __restrict__ a1, u16* __restrict__ o1, int n1,
                       const float* __restrict__ a2, u16* __restrict__ o2, int n2){
    int i = blockIdx.x * blockDim.x + threadIdx.x;
    int stride = gridDim.x * blockDim.x;
    int nt = n0 + n1 + n2;
    for (; i < nt; i += stride){
        const float4* src; ushort4* dst; int j;
        if (i < n0){ src = (const float4*)a0; dst = (ushort4*)o0; j = i; }
        else if (i < n0 + n1){ src = (const float4*)a1; dst = (ushort4*)o1; j = i - n0; }
        else { src = (const float4*)a2; dst = (ushort4*)o2; j = i - n0 - n1; }
        float4 v = src[j];
        ushort4 r; r.x = f2h(v.x); r.y = f2h(v.y); r.z = f2h(v.z); r.w = f2h(v.w);
        dst[j] = r;
    }
}

// ---------------- GEMM 128x128 (R8-exact, best measured: 785 TF) ----------------
// Counted-vmcnt triple buffer: raw barriers + s_waitcnt vmcnt(8).
//   barrier A : all waves done READING buf ct (read last iter)
//   stage K_{t+2} -> ct ; vmcnt(8) = own K_t loads landed  [tail 4 / 0]
//   barrier B : everyone's K_t loads landed ; ds_read + 16 MFMA
// LDS XOR swizzle both sides (global source col + ds_read col) -> 0 conflicts.
template<int OUTH>
__global__ __launch_bounds__(256) void k_gemm_bt(
    const u16* __restrict__ A, const u16* __restrict__ Bw,
    float* __restrict__ outf, u16* __restrict__ outb,
    const float* __restrict__ bias, int M, int N, int K)
{
    __shared__ u16 As[3][128 * 32];
    __shared__ u16 Bs[3][128 * 32];
    const int tid  = threadIdx.x;
    const int brow = blockIdx.y * 128;
    const int bcol = blockIdx.x * 128;
    const int w = tid >> 6, lane = tid & 63;
    const int wr = w >> 1, wc = w & 1;
    const int l15 = lane & 15, g = lane >> 4;
    const int sr  = tid >> 2;
    const int scz = ((tid & 3) ^ ((tid >> 3) & 3)) * 8;
    const int gx  = (g ^ ((l15 >> 1) & 3)) * 8;

    f32x4 acc[4][4];
    #pragma unroll
    for (int i = 0; i < 4; i++)
        #pragma unroll
        for (int j = 0; j < 4; j++){
            f32x4 z = {0.f, 0.f, 0.f, 0.f};
            acc[i][j] = z;
        }

    auto stage = [&](int buf, int k0){
        gld16(&Bw[(size_t)(bcol + sr) * K + k0 + scz],      &Bs[buf][w * 512]);
        gld16(&Bw[(size_t)(bcol + sr + 64) * K + k0 + scz], &Bs[buf][2048 + w * 512]);
        gld16(&A [(size_t)(brow + sr) * K + k0 + scz],      &As[buf][w * 512]);
        gld16(&A [(size_t)(brow + sr + 64) * K + k0 + scz], &As[buf][2048 + w * 512]);
    };

    stage(0, 0);
    stage(1, 32);
    int c = 0;
    for (int k0 = 0; k0 < K; k0 += 32){
        SB0();
        __builtin_amdgcn_s_barrier();          // A
        SB0();
        int ct = c + 2; if (ct >= 3) ct -= 3;
        if (k0 + 64 < K){
            stage(ct, k0 + 64);
            asm volatile("s_waitcnt vmcnt(8)" ::: "memory");
        } else if (k0 + 32 < K){
            asm volatile("s_waitcnt vmcnt(4)" ::: "memory");
        } else {
            asm volatile("s_waitcnt vmcnt(0)" ::: "memory");
        }
        SB0();
        __builtin_amdgcn_s_barrier();          // B
        SB0();
        f16x8 fb[4];
        #pragma unroll
        for (int j = 0; j < 4; j++){
            int row = wc * 64 + j * 16 + l15;
            fb[j] = *(const f16x8*)&Bs[c][row * 32 + gx];
        }
        #pragma unroll
        for (int i = 0; i < 4; i++){
            int row = wr * 64 + i * 16 + l15;
            f16x8 fa = *(const f16x8*)&As[c][row * 32 + gx];
            #pragma unroll
            for (int j = 0; j < 4; j++) acc[i][j] = MFMA(fa, fb[j], acc[i][j]);
        }
        c = (c + 1 == 3) ? 0 : c + 1;
    }

    #pragma unroll
    for (int i = 0; i < 4; i++){
        #pragma unroll
        for (int j = 0; j < 4; j++){
            int colg = bcol + wc * 64 + j * 16 + l15;
            #pragma unroll
            for (int r = 0; r < 4; r++){
                int rowg = brow + wr * 64 + i * 16 + 4 * g + r;
                float v = acc[i][j][r];
                if (OUTH) outb[(size_t)rowg * N + colg] = f2h(v);
                else      outf[(size_t)rowg * N + colg] = v + bias[colg];
            }
        }
    }
}

// ---------------- RMSNorm + RoPE (q,k only) -> (B,H,N,D), fp16 ----------------
// q is pre-scaled by D^-0.5 * log2(e) so attention can exp2 directly.
__global__ __launch_bounds__(256) void k_norm_rope(
    const u16* __restrict__ qkv, const float* __restrict__ qw, const float* __restrict__ kw,
    const float* __restrict__ cosb, const float* __restrict__ sinb,
    u16* __restrict__ qout, u16* __restrict__ kout)
{
    const int m = blockIdx.x;           // 0..4095  (b*N + n)
    const int b = m >> 11;
    const int n = m & 2047;
    const int t = threadIdx.x;
    const size_t base = (size_t)m * FF;
    const int e0 = t * 8;
    const float SCL = 0.08838834764831845f * 1.4426950408889634f;

    float qv[8], kvv[8];
    uint4 qa = *(const uint4*)&qkv[base + e0];
    uint4 ka = *(const uint4*)&qkv[base + CC + e0];
    {
        u32 aa[4] = {qa.x, qa.y, qa.z, qa.w};
        u32 bb[4] = {ka.x, ka.y, ka.z, ka.w};
        #pragma unroll
        for (int i = 0; i < 4; i++){
            qv[2*i]   = h2f((u16)(aa[i] & 0xffff));
            qv[2*i+1] = h2f((u16)(aa[i] >> 16));
            kvv[2*i]   = h2f((u16)(bb[i] & 0xffff));
            kvv[2*i+1] = h2f((u16)(bb[i] >> 16));
        }
    }
    float sq = 0.f, sk = 0.f;
    #pragma unroll
    for (int i = 0; i < 8; i++){ sq += qv[i]*qv[i]; sk += kvv[i]*kvv[i]; }
    #pragma unroll
    for (int o = 32; o > 0; o >>= 1){ sq += __shfl_xor(sq, o); sk += __shfl_xor(sk, o); }
    __shared__ float red[8];
    if ((t & 63) == 0){ red[(t >> 6)*2] = sq; red[(t >> 6)*2 + 1] = sk; }
    __syncthreads();
    sq = red[0] + red[2] + red[4] + red[6];
    sk = red[1] + red[3] + red[5] + red[7];
    const float rq = rsqrtf(sq * (1.f / 2048.f) + 1e-5f);
    const float rk = rsqrtf(sk * (1.f / 2048.f) + 1e-5f);

    const int h  = t >> 4;
    const int d0 = (t & 15) * 8;
    const float* cp = cosb + (size_t)n * DD + d0;
    const float* sp = sinb + (size_t)n * DD + d0;
    float qo[8], ko[8];
    #pragma unroll
    for (int j = 0; j < 8; j += 2){
        float c0 = cp[j], c1 = cp[j+1], s0 = sp[j], s1 = sp[j+1];
        float x0 = qv[j]   * rq * qw[e0 + j];
        float x1 = qv[j+1] * rq * qw[e0 + j + 1];
        qo[j]   = (x0 * c0 - x1 * s0) * SCL;
        qo[j+1] = (x1 * c1 + x0 * s1) * SCL;
        float y0 = kvv[j]   * rk * kw[e0 + j];
        float y1 = kvv[j+1] * rk * kw[e0 + j + 1];
        ko[j]   = y0 * c0 - y1 * s0;
        ko[j+1] = y1 * c1 + y0 * s1;
    }
    const size_t obase = ((size_t)(b * HH + h) * NN + n) * DD + d0;
    uint4 pq, pk;
    pq.x = (u32)f2h(qo[0]) | ((u32)f2h(qo[1]) << 16);
    pq.y = (u32)f2h(qo[2]) | ((u32)f2h(qo[3]) << 16);
    pq.z = (u32)f2h(qo[4]) | ((u32)f2h(qo[5]) << 16);
    pq.w = (u32)f2h(qo[6]) | ((u32)f2h(qo[7]) << 16);
    pk.x = (u32)f2h(ko[0]) | ((u32)f2h(ko[1]) << 16);
    pk.y = (u32)f2h(ko[2]) | ((u32)f2h(ko[3]) << 16);
    pk.z = (u32)f2h(ko[4]) | ((u32)f2h(ko[5]) << 16);
    pk.w = (u32)f2h(ko[6]) | ((u32)f2h(ko[7]) << 16);
    *(uint4*)&qout[obase] = pq;
    *(uint4*)&kout[obase] = pk;
}

// ---------------- V transpose: qkv v-slice (B,N,H,D) -> (BH, D, N) ----------------
__global__ __launch_bounds__(256) void k_vtrans(const u16* __restrict__ qkv, u16* __restrict__ Vt){
    __shared__ u16 t[64 * 66];
    const int bh = blockIdx.z;
    const int b = bh >> 4, h = bh & 15;
    const int n0 = blockIdx.x * 64, d0 = blockIdx.y * 64;
    const int tid = threadIdx.x;
    const int q = tid & 7, p = tid >> 3;
    #pragma unroll
    for (int it = 0; it < 2; it++){
        int r = p + it * 32;
        const u16* src = qkv + (size_t)(b * NN + n0 + r) * FF + 2 * CC + h * DD + d0 + q * 8;
        uint4 v = *(const uint4*)src;
        u32* dst = (u32*)&t[r * 66 + q * 8];
        dst[0] = v.x; dst[1] = v.y; dst[2] = v.z; dst[3] = v.w;
    }
    __syncthreads();
    #pragma unroll
    for (int it = 0; it < 2; it++){
        int rd = p + it * 32;
        u16 o[8];
        #pragma unroll
        for (int j = 0; j < 8; j++) o[j] = t[(q * 8 + j) * 66 + rd];
        *(uint4*)(Vt + ((size_t)bh * DD + d0 + rd) * NN + n0 + q * 8) = *(uint4*)o;
    }
}

// ---------------- attention v6 (R11-exact): LDS-staged K/V, 2-phase dbuf ----------
__global__ __launch_bounds__(256, 2) void k_attn6(
    const u16* __restrict__ Q, const u16* __restrict__ Kt, const u16* __restrict__ Vt2,
    u16* __restrict__ O)
{
    __shared__ u16 Kbuf[2][8192];   // 16 slots: s = hh*8 + t*4 + c
    __shared__ u16 Vbuf[2][8192];   // 16 slots: s = hh*8 + tb
    const int tid = threadIdx.x;
    const int w = tid >> 6, lane = tid & 63;
    const int l15 = lane & 15, g = lane >> 4;
    const int flat = blockIdx.x;
    const int lid  = (flat & 7) * 64 + (flat >> 3);   // bijective XCD swizzle (512 blocks)
    const int qb = lid & 15;
    const int h  = (lid >> 4) & 15;
    const int b  = lid >> 8;
    const size_t hb  = (size_t)(b * HH + h) * NN * DD;  // Q, K: (N,D)
    const size_t hbT = (size_t)(b * HH + h) * DD * NN;  // Vt2: (D,N)
    const int qbase = qb * 128 + w * 32;
    const int mperm = 8 * (l15 >> 2) + (l15 & 3);

    f16x8 qf[2][4];
    #pragma unroll
    for (int u = 0; u < 2; u++){
        const u16* qrow = Q + hb + (size_t)(qbase + u * 16 + l15) * DD;
        #pragma unroll
        for (int c = 0; c < 4; c++)
            qf[u][c] = *(const f16x8*)(qrow + c * 32 + 8 * g);
    }

    f32x4 oacc[2][8];
    #pragma unroll
    for (int u = 0; u < 2; u++)
        #pragma unroll
        for (int tb = 0; tb < 8; tb++){ f32x4 z = {0.f,0.f,0.f,0.f}; oacc[u][tb] = z; }
    float lsum0 = 0.f, lsum1 = 0.f;

    auto stage = [&](int buf, int kv0){
        #pragma unroll
        for (int it = 0; it < 8; it++){
            int s = it * 4 + w;                 // 0..31, each slot once
            if (s < 16){
                int hh = s >> 3, t = (s >> 2) & 1, c = s & 3;
                gld16(&Kt[hb + (size_t)(kv0 + 32 * hh + 4 * t + mperm) * DD + 32 * c + 8 * g],
                      &Kbuf[buf][s * 512]);
            } else {
                int s2 = s - 16;
                int hh = s2 >> 3, tb = s2 & 7;
                gld16(&Vt2[hbT + (size_t)(tb * 16 + l15) * NN + kv0 + 32 * hh + 8 * g],
                      &Vbuf[buf][s2 * 512]);
            }
        }
    };

    int cur = 0;
    stage(0, 0);
    for (int kv0 = 0; kv0 < NN; kv0 += 64){
        __syncthreads();                         // buf[cur] staged; prev reads done
        if (kv0 + 64 < NN) stage(cur ^ 1, kv0 + 64);
        const u16* kb = &Kbuf[cur][0] + lane * 8;
        const u16* vb = &Vbuf[cur][0] + lane * 8;

        f32x4 st[2][4];
        #pragma unroll
        for (int hh = 0; hh < 2; hh++)
            #pragma unroll
            for (int q = 0; q < 4; q++){ f32x4 z = {0.f,0.f,0.f,0.f}; st[hh][q] = z; }
        __builtin_amdgcn_s_setprio(1);
        #pragma unroll
        for (int hh = 0; hh < 2; hh++){
            #pragma unroll
            for (int c = 0; c < 4; c++){
                f16x8 kf0 = *(const f16x8*)(kb + (hh * 8 + c) * 512);
                f16x8 kf1 = *(const f16x8*)(kb + (hh * 8 + 4 + c) * 512);
                st[hh][0] = MFMA(kf0, qf[0][c], st[hh][0]);
                st[hh][1] = MFMA(kf0, qf[1][c], st[hh][1]);
                st[hh][2] = MFMA(kf1, qf[0][c], st[hh][2]);
                st[hh][3] = MFMA(kf1, qf[1][c], st[hh][3]);
            }
        }
        __builtin_amdgcn_s_setprio(0);

        f16x8 pf[2][2];
        #pragma unroll
        for (int hh = 0; hh < 2; hh++){
            #pragma unroll
            for (int r = 0; r < 4; r++){
                float e00 = exp2f(st[hh][0][r]), e10 = exp2f(st[hh][2][r]);
                float e01 = exp2f(st[hh][1][r]), e11 = exp2f(st[hh][3][r]);
                lsum0 += e00 + e10;
                lsum1 += e01 + e11;
                pf[hh][0][r] = (f16_t)e00; pf[hh][0][r + 4] = (f16_t)e10;
                pf[hh][1][r] = (f16_t)e01; pf[hh][1][r + 4] = (f16_t)e11;
            }
        }

        __builtin_amdgcn_s_setprio(1);
        #pragma unroll
        for (int hh = 0; hh < 2; hh++){
            #pragma unroll
            for (int tb = 0; tb < 8; tb++){
                f16x8 vf = *(const f16x8*)(vb + (hh * 8 + tb) * 512);
                oacc[0][tb] = MFMA(pf[hh][0], vf, oacc[0][tb]);
                oacc[1][tb] = MFMA(pf[hh][1], vf, oacc[1][tb]);
            }
        }
        __builtin_amdgcn_s_setprio(0);
        cur ^= 1;
    }

    lsum0 += __shfl_xor(lsum0, 16); lsum0 += __shfl_xor(lsum0, 32);
    lsum1 += __shfl_xor(lsum1, 16); lsum1 += __shfl_xor(lsum1, 32);
    float linv0 = 1.f / lsum0, linv1 = 1.f / lsum1;
    float li0[4], li1[4];
    #pragma unroll
    for (int r = 0; r < 4; r++){
        li0[r] = __shfl(linv0, 4 * g + r);
        li1[r] = __shfl(linv1, 4 * g + r);
    }

    #pragma unroll
    for (int tb = 0; tb < 8; tb++){
        #pragma unroll
        for (int r = 0; r < 4; r++){
            int q0 = qbase + 4 * g + r;
            O[(size_t)(b * NN + q0) * CC + h * DD + tb * 16 + l15] = f2h(oacc[0][tb][r] * li0[r]);
            int q1 = qbase + 16 + 4 * g + r;
            O[(size_t)(b * NN + q1) * CC + h * DD + tb * 16 + l15] = f2h(oacc[1][tb][r] * li1[r]);
        }
    }
}

// ---------------- launch ----------------
extern "C" void kernel_launch(void* const* d_in, const int* in_sizes, int n_in,
                              void* d_out, int out_size, void* d_ws, size_t ws_size,
                              hipStream_t stream) {
    const float* x      = (const float*)d_in[0];
    const float* w_qkv  = (const float*)d_in[1];
    const float* qw     = (const float*)d_in[2];
    const float* kw     = (const float*)d_in[3];
    const float* cosb   = (const float*)d_in[4];
    const float* sinb   = (const float*)d_in[5];
    const float* w_proj = (const float*)d_in[6];
    const float* b_proj = (const float*)d_in[7];
    float* out = (float*)d_out;

    const size_t sz_xh   = (size_t)MM * CC * 2;        // 16 MiB
    const size_t sz_wqkv = (size_t)FF * CC * 2;        // 24 MiB
    const size_t sz_wprj = (size_t)CC * CC * 2;        // 8 MiB
    const size_t sz_qkv  = (size_t)MM * FF * 2;        // 48 MiB
    const size_t sz_t    = (size_t)BB * HH * NN * DD * 2; // 16 MiB each
    const size_t need = sz_xh + sz_wqkv + sz_wprj + sz_qkv + sz_t*3 + sz_xh;
    if (ws_size < need) return;

    char* ws = (char*)d_ws;
    size_t off = 0;
    auto alloc = [&](size_t bytes){ void* p = ws + off; off += (bytes + 255) & ~(size_t)255; return p; };
    u16* x_h     = (u16*)alloc(sz_xh);
    u16* wqkv_h  = (u16*)alloc(sz_wqkv);
    u16* wprj_h  = (u16*)alloc(sz_wprj);
    u16* qkv     = (u16*)alloc(sz_qkv);
    u16* qr      = (u16*)alloc(sz_t);
    u16* kr      = (u16*)alloc(sz_t);
    u16* vt2     = (u16*)alloc(sz_t);   // transposed V (B,H,D,N), read from qkv directly
    u16* ob      = (u16*)alloc(sz_xh);

    k_f2h3<<<2048, 256, 0, stream>>>(x, x_h, MM * CC / 4,
                                     w_qkv, wqkv_h, FF * CC / 4,
                                     w_proj, wprj_h, CC * CC / 4);
    k_gemm_bt<1><<<dim3(FF / 128, MM / 128), 256, 0, stream>>>(
        x_h, wqkv_h, nullptr, qkv, nullptr, MM, FF, CC);
    k_norm_rope<<<MM, 256, 0, stream>>>(qkv, qw, kw, cosb, sinb, qr, kr);
    k_vtrans<<<dim3(NN / 64, DD / 64, BB * HH), 256, 0, stream>>>(qkv, vt2);
    k_attn6<<<512, 256, 0, stream>>>(qr, kr, vt2, ob);
    k_gemm_bt<0><<<dim3(CC / 128, MM / 128), 256, 0, stream>>>(
        ob, wprj_h, out, nullptr, b_proj, MM, CC, CC);
}

// Round 15
// 305.457 us; speedup vs baseline: 1.1914x; 1.0278x over previous
//
#include <hip/hip_runtime.h>
#include <stdint.h>

typedef unsigned short u16;
typedef unsigned int   u32;
typedef _Float16 f16_t;
typedef f16_t f16x8 __attribute__((ext_vector_type(8)));
typedef float  f32x4  __attribute__((ext_vector_type(4)));

#define BB 2
#define NN 2048
#define CC 2048
#define HH 16
#define DD 128
#define FF 6144
#define MM 4096

__device__ __forceinline__ u16 f2h(float f){
    f16_t h = (f16_t)f;
    return __builtin_bit_cast(u16, h);
}
__device__ __forceinline__ float h2f(u16 b){
    return (float)__builtin_bit_cast(f16_t, b);
}
__device__ __forceinline__ f32x4 MFMA(f16x8 a, f16x8 b, f32x4 c){
    return __builtin_amdgcn_mfma_f32_16x16x32_f16(a, b, c, 0, 0, 0);
}
__device__ __forceinline__ void gld16(const void* g, void* l){
    __builtin_amdgcn_global_load_lds(
        (const __attribute__((address_space(1))) void*)(g),
        (__attribute__((address_space(3))) void*)(l), 16, 0, 0);
}
#define SB0() __builtin_amdgcn_sched_barrier(0)

// ---------------- fp32 -> fp16 conversion (x, w_qkv, w_proj in one launch) ----
__global__ void k_f2h3(const float* __restrict__ a0, u16* __restrict__ o0, int n0,
                       const float* __restrict__ a1, u16* __restrict__ o1, int n1,
                       const float* __restrict__ a2, u16* __restrict__ o2, int n2){
    int i = blockIdx.x * blockDim.x + threadIdx.x;
    int stride = gridDim.x * blockDim.x;
    int nt = n0 + n1 + n2;
    for (; i < nt; i += stride){
        const float4* src; ushort4* dst; int j;
        if (i < n0){ src = (const float4*)a0; dst = (ushort4*)o0; j = i; }
        else if (i < n0 + n1){ src = (const float4*)a1; dst = (ushort4*)o1; j = i - n0; }
        else { src = (const float4*)a2; dst = (ushort4*)o2; j = i - n0 - n1; }
        float4 v = src[j];
        ushort4 r; r.x = f2h(v.x); r.y = f2h(v.y); r.z = f2h(v.z); r.w = f2h(v.w);
        dst[j] = r;
    }
}

// ---------------- GEMM 128x128 (R8-exact schedule; fused V-transpose epilogue) --
// Counted-vmcnt triple buffer: raw barriers + s_waitcnt vmcnt(8).
//   barrier A : all waves done READING buf ct (read last iter)
//   stage K_{t+2} -> ct ; vmcnt(8) = own K_t loads landed  [tail 4 / 0]
//   barrier B : everyone's K_t loads landed ; ds_read + 16 MFMA
// LDS XOR swizzle both sides (global source col + ds_read col) -> 0 conflicts.
// Epilogue: for QKV (OUTH=1), V-column blocks (bcol >= 2*CC) cover exactly one
// head x 128 consecutive tokens -> write directly transposed into vt2 (B,H,D,N),
// eliminating the separate k_vtrans pass. Values bit-identical (same f2h(acc)).
template<int OUTH>
__global__ __launch_bounds__(256) void k_gemm_bt(
    const u16* __restrict__ A, const u16* __restrict__ Bw,
    float* __restrict__ outf, u16* __restrict__ outb, u16* __restrict__ vt2o,
    const float* __restrict__ bias, int M, int N, int K)
{
    __shared__ u16 As[3][128 * 32];
    __shared__ u16 Bs[3][128 * 32];
    const int tid  = threadIdx.x;
    const int brow = blockIdx.y * 128;
    const int bcol = blockIdx.x * 128;
    const int w = tid >> 6, lane = tid & 63;
    const int wr = w >> 1, wc = w & 1;
    const int l15 = lane & 15, g = lane >> 4;
    const int sr  = tid >> 2;
    const int scz = ((tid & 3) ^ ((tid >> 3) & 3)) * 8;
    const int gx  = (g ^ ((l15 >> 1) & 3)) * 8;

    f32x4 acc[4][4];
    #pragma unroll
    for (int i = 0; i < 4; i++)
        #pragma unroll
        for (int j = 0; j < 4; j++){
            f32x4 z = {0.f, 0.f, 0.f, 0.f};
            acc[i][j] = z;
        }

    auto stage = [&](int buf, int k0){
        gld16(&Bw[(size_t)(bcol + sr) * K + k0 + scz],      &Bs[buf][w * 512]);
        gld16(&Bw[(size_t)(bcol + sr + 64) * K + k0 + scz], &Bs[buf][2048 + w * 512]);
        gld16(&A [(size_t)(brow + sr) * K + k0 + scz],      &As[buf][w * 512]);
        gld16(&A [(size_t)(brow + sr + 64) * K + k0 + scz], &As[buf][2048 + w * 512]);
    };

    stage(0, 0);
    stage(1, 32);
    int c = 0;
    for (int k0 = 0; k0 < K; k0 += 32){
        SB0();
        __builtin_amdgcn_s_barrier();          // A
        SB0();
        int ct = c + 2; if (ct >= 3) ct -= 3;
        if (k0 + 64 < K){
            stage(ct, k0 + 64);
            asm volatile("s_waitcnt vmcnt(8)" ::: "memory");
        } else if (k0 + 32 < K){
            asm volatile("s_waitcnt vmcnt(4)" ::: "memory");
        } else {
            asm volatile("s_waitcnt vmcnt(0)" ::: "memory");
        }
        SB0();
        __builtin_amdgcn_s_barrier();          // B
        SB0();
        f16x8 fb[4];
        #pragma unroll
        for (int j = 0; j < 4; j++){
            int row = wc * 64 + j * 16 + l15;
            fb[j] = *(const f16x8*)&Bs[c][row * 32 + gx];
        }
        #pragma unroll
        for (int i = 0; i < 4; i++){
            int row = wr * 64 + i * 16 + l15;
            f16x8 fa = *(const f16x8*)&As[c][row * 32 + gx];
            #pragma unroll
            for (int j = 0; j < 4; j++) acc[i][j] = MFMA(fa, fb[j], acc[i][j]);
        }
        c = (c + 1 == 3) ? 0 : c + 1;
    }

    if (OUTH && bcol >= 2 * CC){
        // V block: write transposed into vt2 (B,H,D,N).
        const int h  = (bcol - 2 * CC) >> 7;      // one head per block (128-aligned)
        const int b  = brow >> 11;                 // one batch per block
        const int n0 = brow & (NN - 1);
        u16* vbase = vt2o + (size_t)(b * HH + h) * DD * NN;
        #pragma unroll
        for (int i = 0; i < 4; i++){
            #pragma unroll
            for (int j = 0; j < 4; j++){
                int d = wc * 64 + j * 16 + l15;
                #pragma unroll
                for (int r = 0; r < 4; r++){
                    int n = n0 + wr * 64 + i * 16 + 4 * g + r;
                    vbase[(size_t)d * NN + n] = f2h(acc[i][j][r]);
                }
            }
        }
    } else {
        #pragma unroll
        for (int i = 0; i < 4; i++){
            #pragma unroll
            for (int j = 0; j < 4; j++){
                int colg = bcol + wc * 64 + j * 16 + l15;
                #pragma unroll
                for (int r = 0; r < 4; r++){
                    int rowg = brow + wr * 64 + i * 16 + 4 * g + r;
                    float v = acc[i][j][r];
                    if (OUTH) outb[(size_t)rowg * N + colg] = f2h(v);
                    else      outf[(size_t)rowg * N + colg] = v + bias[colg];
                }
            }
        }
    }
}

// ---------------- RMSNorm + RoPE (q,k only) -> (B,H,N,D), fp16 ----------------
// q is pre-scaled by D^-0.5 * log2(e) so attention can exp2 directly.
__global__ __launch_bounds__(256) void k_norm_rope(
    const u16* __restrict__ qkv, const float* __restrict__ qw, const float* __restrict__ kw,
    const float* __restrict__ cosb, const float* __restrict__ sinb,
    u16* __restrict__ qout, u16* __restrict__ kout)
{
    const int m = blockIdx.x;           // 0..4095  (b*N + n)
    const int b = m >> 11;
    const int n = m & 2047;
    const int t = threadIdx.x;
    const size_t base = (size_t)m * FF;
    const int e0 = t * 8;
    const float SCL = 0.08838834764831845f * 1.4426950408889634f;

    float qv[8], kvv[8];
    uint4 qa = *(const uint4*)&qkv[base + e0];
    uint4 ka = *(const uint4*)&qkv[base + CC + e0];
    {
        u32 aa[4] = {qa.x, qa.y, qa.z, qa.w};
        u32 bb[4] = {ka.x, ka.y, ka.z, ka.w};
        #pragma unroll
        for (int i = 0; i < 4; i++){
            qv[2*i]   = h2f((u16)(aa[i] & 0xffff));
            qv[2*i+1] = h2f((u16)(aa[i] >> 16));
            kvv[2*i]   = h2f((u16)(bb[i] & 0xffff));
            kvv[2*i+1] = h2f((u16)(bb[i] >> 16));
        }
    }
    float sq = 0.f, sk = 0.f;
    #pragma unroll
    for (int i = 0; i < 8; i++){ sq += qv[i]*qv[i]; sk += kvv[i]*kvv[i]; }
    #pragma unroll
    for (int o = 32; o > 0; o >>= 1){ sq += __shfl_xor(sq, o); sk += __shfl_xor(sk, o); }
    __shared__ float red[8];
    if ((t & 63) == 0){ red[(t >> 6)*2] = sq; red[(t >> 6)*2 + 1] = sk; }
    __syncthreads();
    sq = red[0] + red[2] + red[4] + red[6];
    sk = red[1] + red[3] + red[5] + red[7];
    const float rq = rsqrtf(sq * (1.f / 2048.f) + 1e-5f);
    const float rk = rsqrtf(sk * (1.f / 2048.f) + 1e-5f);

    const int h  = t >> 4;
    const int d0 = (t & 15) * 8;
    const float* cp = cosb + (size_t)n * DD + d0;
    const float* sp = sinb + (size_t)n * DD + d0;
    float qo[8], ko[8];
    #pragma unroll
    for (int j = 0; j < 8; j += 2){
        float c0 = cp[j], c1 = cp[j+1], s0 = sp[j], s1 = sp[j+1];
        float x0 = qv[j]   * rq * qw[e0 + j];
        float x1 = qv[j+1] * rq * qw[e0 + j + 1];
        qo[j]   = (x0 * c0 - x1 * s0) * SCL;
        qo[j+1] = (x1 * c1 + x0 * s1) * SCL;
        float y0 = kvv[j]   * rk * kw[e0 + j];
        float y1 = kvv[j+1] * rk * kw[e0 + j + 1];
        ko[j]   = y0 * c0 - y1 * s0;
        ko[j+1] = y1 * c1 + y0 * s1;
    }
    const size_t obase = ((size_t)(b * HH + h) * NN + n) * DD + d0;
    uint4 pq, pk;
    pq.x = (u32)f2h(qo[0]) | ((u32)f2h(qo[1]) << 16);
    pq.y = (u32)f2h(qo[2]) | ((u32)f2h(qo[3]) << 16);
    pq.z = (u32)f2h(qo[4]) | ((u32)f2h(qo[5]) << 16);
    pq.w = (u32)f2h(qo[6]) | ((u32)f2h(qo[7]) << 16);
    pk.x = (u32)f2h(ko[0]) | ((u32)f2h(ko[1]) << 16);
    pk.y = (u32)f2h(ko[2]) | ((u32)f2h(ko[3]) << 16);
    pk.z = (u32)f2h(ko[4]) | ((u32)f2h(ko[5]) << 16);
    pk.w = (u32)f2h(ko[6]) | ((u32)f2h(ko[7]) << 16);
    *(uint4*)&qout[obase] = pq;
    *(uint4*)&kout[obase] = pk;
}

// ---------------- attention v6 (R11-exact): LDS-staged K/V, 2-phase dbuf ----------
__global__ __launch_bounds__(256, 2) void k_attn6(
    const u16* __restrict__ Q, const u16* __restrict__ Kt, const u16* __restrict__ Vt2,
    u16* __restrict__ O)
{
    __shared__ u16 Kbuf[2][8192];   // 16 slots: s = hh*8 + t*4 + c
    __shared__ u16 Vbuf[2][8192];   // 16 slots: s = hh*8 + tb
    const int tid = threadIdx.x;
    const int w = tid >> 6, lane = tid & 63;
    const int l15 = lane & 15, g = lane >> 4;
    const int flat = blockIdx.x;
    const int lid  = (flat & 7) * 64 + (flat >> 3);   // bijective XCD swizzle (512 blocks)
    const int qb = lid & 15;
    const int h  = (lid >> 4) & 15;
    const int b  = lid >> 8;
    const size_t hb  = (size_t)(b * HH + h) * NN * DD;  // Q, K: (N,D)
    const size_t hbT = (size_t)(b * HH + h) * DD * NN;  // Vt2: (D,N)
    const int qbase = qb * 128 + w * 32;
    const int mperm = 8 * (l15 >> 2) + (l15 & 3);

    f16x8 qf[2][4];
    #pragma unroll
    for (int u = 0; u < 2; u++){
        const u16* qrow = Q + hb + (size_t)(qbase + u * 16 + l15) * DD;
        #pragma unroll
        for (int c = 0; c < 4; c++)
            qf[u][c] = *(const f16x8*)(qrow + c * 32 + 8 * g);
    }

    f32x4 oacc[2][8];
    #pragma unroll
    for (int u = 0; u < 2; u++)
        #pragma unroll
        for (int tb = 0; tb < 8; tb++){ f32x4 z = {0.f,0.f,0.f,0.f}; oacc[u][tb] = z; }
    float lsum0 = 0.f, lsum1 = 0.f;

    auto stage = [&](int buf, int kv0){
        #pragma unroll
        for (int it = 0; it < 8; it++){
            int s = it * 4 + w;                 // 0..31, each slot once
            if (s < 16){
                int hh = s >> 3, t = (s >> 2) & 1, c = s & 3;
                gld16(&Kt[hb + (size_t)(kv0 + 32 * hh + 4 * t + mperm) * DD + 32 * c + 8 * g],
                      &Kbuf[buf][s * 512]);
            } else {
                int s2 = s - 16;
                int hh = s2 >> 3, tb = s2 & 7;
                gld16(&Vt2[hbT + (size_t)(tb * 16 + l15) * NN + kv0 + 32 * hh + 8 * g],
                      &Vbuf[buf][s2 * 512]);
            }
        }
    };

    int cur = 0;
    stage(0, 0);
    for (int kv0 = 0; kv0 < NN; kv0 += 64){
        __syncthreads();                         // buf[cur] staged; prev reads done
        if (kv0 + 64 < NN) stage(cur ^ 1, kv0 + 64);
        const u16* kb = &Kbuf[cur][0] + lane * 8;
        const u16* vb = &Vbuf[cur][0] + lane * 8;

        f32x4 st[2][4];
        #pragma unroll
        for (int hh = 0; hh < 2; hh++)
            #pragma unroll
            for (int q = 0; q < 4; q++){ f32x4 z = {0.f,0.f,0.f,0.f}; st[hh][q] = z; }
        __builtin_amdgcn_s_setprio(1);
        #pragma unroll
        for (int hh = 0; hh < 2; hh++){
            #pragma unroll
            for (int c = 0; c < 4; c++){
                f16x8 kf0 = *(const f16x8*)(kb + (hh * 8 + c) * 512);
                f16x8 kf1 = *(const f16x8*)(kb + (hh * 8 + 4 + c) * 512);
                st[hh][0] = MFMA(kf0, qf[0][c], st[hh][0]);
                st[hh][1] = MFMA(kf0, qf[1][c], st[hh][1]);
                st[hh][2] = MFMA(kf1, qf[0][c], st[hh][2]);
                st[hh][3] = MFMA(kf1, qf[1][c], st[hh][3]);
            }
        }
        __builtin_amdgcn_s_setprio(0);

        f16x8 pf[2][2];
        #pragma unroll
        for (int hh = 0; hh < 2; hh++){
            #pragma unroll
            for (int r = 0; r < 4; r++){
                float e00 = exp2f(st[hh][0][r]), e10 = exp2f(st[hh][2][r]);
                float e01 = exp2f(st[hh][1][r]), e11 = exp2f(st[hh][3][r]);
                lsum0 += e00 + e10;
                lsum1 += e01 + e11;
                pf[hh][0][r] = (f16_t)e00; pf[hh][0][r + 4] = (f16_t)e10;
                pf[hh][1][r] = (f16_t)e01; pf[hh][1][r + 4] = (f16_t)e11;
            }
        }

        __builtin_amdgcn_s_setprio(1);
        #pragma unroll
        for (int hh = 0; hh < 2; hh++){
            #pragma unroll
            for (int tb = 0; tb < 8; tb++){
                f16x8 vf = *(const f16x8*)(vb + (hh * 8 + tb) * 512);
                oacc[0][tb] = MFMA(pf[hh][0], vf, oacc[0][tb]);
                oacc[1][tb] = MFMA(pf[hh][1], vf, oacc[1][tb]);
            }
        }
        __builtin_amdgcn_s_setprio(0);
        cur ^= 1;
    }

    lsum0 += __shfl_xor(lsum0, 16); lsum0 += __shfl_xor(lsum0, 32);
    lsum1 += __shfl_xor(lsum1, 16); lsum1 += __shfl_xor(lsum1, 32);
    float linv0 = 1.f / lsum0, linv1 = 1.f / lsum1;
    float li0[4], li1[4];
    #pragma unroll
    for (int r = 0; r < 4; r++){
        li0[r] = __shfl(linv0, 4 * g + r);
        li1[r] = __shfl(linv1, 4 * g + r);
    }

    #pragma unroll
    for (int tb = 0; tb < 8; tb++){
        #pragma unroll
        for (int r = 0; r < 4; r++){
            int q0 = qbase + 4 * g + r;
            O[(size_t)(b * NN + q0) * CC + h * DD + tb * 16 + l15] = f2h(oacc[0][tb][r] * li0[r]);
            int q1 = qbase + 16 + 4 * g + r;
            O[(size_t)(b * NN + q1) * CC + h * DD + tb * 16 + l15] = f2h(oacc[1][tb][r] * li1[r]);
        }
    }
}

// ---------------- launch ----------------
extern "C" void kernel_launch(void* const* d_in, const int* in_sizes, int n_in,
                              void* d_out, int out_size, void* d_ws, size_t ws_size,
                              hipStream_t stream) {
    const float* x      = (const float*)d_in[0];
    const float* w_qkv  = (const float*)d_in[1];
    const float* qw     = (const float*)d_in[2];
    const float* kw     = (const float*)d_in[3];
    const float* cosb   = (const float*)d_in[4];
    const float* sinb   = (const float*)d_in[5];
    const float* w_proj = (const float*)d_in[6];
    const float* b_proj = (const float*)d_in[7];
    float* out = (float*)d_out;

    const size_t sz_xh   = (size_t)MM * CC * 2;        // 16 MiB
    const size_t sz_wqkv = (size_t)FF * CC * 2;        // 24 MiB
    const size_t sz_wprj = (size_t)CC * CC * 2;        // 8 MiB
    const size_t sz_qkv  = (size_t)MM * FF * 2;        // 48 MiB
    const size_t sz_t    = (size_t)BB * HH * NN * DD * 2; // 16 MiB each
    const size_t need = sz_xh + sz_wqkv + sz_wprj + sz_qkv + sz_t*3 + sz_xh;
    if (ws_size < need) return;

    char* ws = (char*)d_ws;
    size_t off = 0;
    auto alloc = [&](size_t bytes){ void* p = ws + off; off += (bytes + 255) & ~(size_t)255; return p; };
    u16* x_h     = (u16*)alloc(sz_xh);
    u16* wqkv_h  = (u16*)alloc(sz_wqkv);
    u16* wprj_h  = (u16*)alloc(sz_wprj);
    u16* qkv     = (u16*)alloc(sz_qkv);
    u16* qr      = (u16*)alloc(sz_t);
    u16* kr      = (u16*)alloc(sz_t);
    u16* vt2     = (u16*)alloc(sz_t);   // transposed V (B,H,D,N), written by QKV GEMM
    u16* ob      = (u16*)alloc(sz_xh);

    k_f2h3<<<2048, 256, 0, stream>>>(x, x_h, MM * CC / 4,
                                     w_qkv, wqkv_h, FF * CC / 4,
                                     w_proj, wprj_h, CC * CC / 4);
    k_gemm_bt<1><<<dim3(FF / 128, MM / 128), 256, 0, stream>>>(
        x_h, wqkv_h, nullptr, qkv, vt2, nullptr, MM, FF, CC);
    k_norm_rope<<<MM, 256, 0, stream>>>(qkv, qw, kw, cosb, sinb, qr, kr);
    k_attn6<<<512, 256, 0, stream>>>(qr, kr, vt2, ob);
    k_gemm_bt<0><<<dim3(CC / 128, MM / 128), 256, 0, stream>>>(
        ob, wprj_h, out, nullptr, nullptr, b_proj, MM, CC, CC);
}